// Round 7
// baseline (75.172 us; speedup 1.0000x reference)
//
#include <hip/hip_runtime.h>
#include <hip/hip_bf16.h>

#define L2E 1.4426950408889634f
#define LN2 0.6931471805599453f

#if defined(__has_builtin)
#if __has_builtin(__builtin_amdgcn_exp2f)
#define EXP2(x) __builtin_amdgcn_exp2f(x)
#else
#define EXP2(x) exp2f(x)
#endif
#if __has_builtin(__builtin_amdgcn_logf)
#define LOG2(x) __builtin_amdgcn_logf(x)
#else
#define LOG2(x) __log2f(x)
#endif
#else
#define EXP2(x) exp2f(x)
#define LOG2(x) __log2f(x)
#endif

typedef __attribute__((ext_vector_type(8))) short bf16x8;
typedef __attribute__((ext_vector_type(4))) float f32x4;
typedef __attribute__((ext_vector_type(2))) float f32x2;

__device__ __forceinline__ void gld_lds16(const void* g, void* l) {
  __builtin_amdgcn_global_load_lds(
      (const __attribute__((address_space(1))) void*)g,
      (__attribute__((address_space(3))) void*)l, 16, 0, 0);
}

__device__ __forceinline__ unsigned bf16rne(float f) {
  unsigned u = __float_as_uint(f);
  return (u + 0x7fffu + ((u >> 16) & 1u)) >> 16;
}

// Kernel A: L2-normalize embedding table -> packed bf16 (2 per uint32).
// float4 loads, 2 rows per wave (lanes 0-31 row r, lanes 32-63 row r+1).
// At HBM floor: 25.6MB read + 12.8MB write ~= 6.1us.
__global__ __launch_bounds__(256) void knrm_norm(const float* __restrict__ emb,
                                                 unsigned* __restrict__ embN) {
  const int t = threadIdx.x;
  const int l = t & 31;
  const int sub = (t >> 5) & 1;
  int wv = blockIdx.x * 4 + (t >> 6);
  const int nW = gridDim.x * 4;
  for (int rp = wv; rp < 25000; rp += nW) {
    int r = rp * 2 + sub;
    float4 v = *(const float4*)(emb + (size_t)r * 128 + l * 4);
    float ss = v.x * v.x + v.y * v.y + v.z * v.z + v.w * v.w;
#pragma unroll
    for (int m = 1; m < 32; m <<= 1) ss += __shfl_xor(ss, m, 64);  // within 32-lane half
    float sc = 1.0f / fmaxf(sqrtf(ss), 1e-12f);
    uint2 o;
    o.x = bf16rne(v.x * sc) | (bf16rne(v.y * sc) << 16);
    o.y = bf16rne(v.z * sc) | (bf16rne(v.w * sc) << 16);
    *(uint2*)(embN + (size_t)r * 64 + l * 2) = o;
  }
}

// Kernel B: per batch item, 512 threads (8 waves) for 8 waves/SIMD occupancy.
// Docs staged in 32-row eighths (double-buffered LDS via global_load_lds,
// ONE gld per thread per stage). Wave group g (w>>2) computes rows g*16..+15
// of each stage; q-strip = (w&3)*16. mm^T via mfma_f32_16x16x32_bf16.
// 20 Gaussian kernels via middle-out geometric chain, packed f32x2.
// Exact-match kernel = integer token compare (group 0 only).
__global__ __launch_bounds__(512, 8) void knrm_main(
    const int* __restrict__ query, const int* __restrict__ doc,
    const unsigned* __restrict__ embN,
    const float* __restrict__ W1, const float* __restrict__ b1,
    const float* __restrict__ W2, const float* __restrict__ b2,
    const float* __restrict__ W3, const float* __restrict__ b3,
    float* __restrict__ out) {
  __shared__ __align__(16) char dbuf[2][32 * 256];  // 2 x 8KB doc eighths
  __shared__ float kmbuf[2][64][21];                // per-group partial raw sums
  __shared__ int dtok[256];
  __shared__ float km2[4][21];
  __shared__ float kmv[21];
  __shared__ float x1[10];
  __shared__ float x2[5];

  const int b = blockIdx.x;
  const int tid = threadIdx.x;
  const int w = tid >> 6;       // wave 0..7
  const int lane = tid & 63;
  const int lo = lane & 15, hi = lane >> 4;
  const int qs = w & 3;         // q strip (16 rows)
  const int g = w >> 2;         // doc-row group within a stage
  const char* embB = (const char*)embN;  // 256 B per vocab row (128 bf16)

  if (tid < 256) dtok[tid] = doc[b * 256 + tid];

  // ---- Q fragments straight from global (B-operand: col=lo=q, k=8*hi+e) ----
  const int myq = query[b * 64 + qs * 16 + lo];
  bf16x8 bq[4];
#pragma unroll
  for (int kk = 0; kk < 4; ++kk)
    bq[kk] = *(const bf16x8*)(embB + (size_t)myq * 256 + kk * 64 + hi * 16);

  // ---- staging geometry: each thread owns one 16B slot of the 32-row tile.
  // LDS rows are 256B; slots XOR-swizzled: LDS[row][s] = G[row][s^(row&7)].
  // global_load_lds writes linearly (wave-uniform base + lane*16), so the
  // SOURCE slot is pre-swizzled.
  const int srow = w * 4 + (lane >> 4);        // 0..31
  const int sslot = (lane & 15) ^ (srow & 7);  // pre-swizzled source slot
  {
    int tok = doc[b * 256 + srow];
    gld_lds16(embB + (size_t)tok * 256 + sslot * 16, dbuf[0] + w * 1024);
  }
  asm volatile("s_waitcnt vmcnt(0)" ::: "memory");
  __syncthreads();

  f32x2 acc20[20];  // packed accumulators: .x sums elems (e=0,2), .y (e=1,3)
#pragma unroll
  for (int j = 0; j < 20; ++j) acc20[j] = (f32x2){0.0f, 0.0f};

#pragma unroll 1
  for (int s = 0; s < 8; ++s) {
    const int cur = s & 1;
    // prefetch next eighth into the other buffer (overlaps compute below;
    // safe: the barrier ending stage s-1 guaranteed all reads of it finished)
    if (s < 7) {
      int tok = doc[b * 256 + (s + 1) * 32 + srow];
      gld_lds16(embB + (size_t)tok * 256 + sslot * 16, dbuf[cur ^ 1] + w * 1024);
    }
    // one 16x16 doc tile per wave: rows g*16..g*16+15 of this stage
    f32x4 mm = {0.0f, 0.0f, 0.0f, 0.0f};
#pragma unroll
    for (int kk = 0; kk < 4; ++kk) {
      int row = g * 16 + lo;  // A-operand: row=lo within tile, k=8*hi+e
      int slot = (kk * 4 + hi) ^ (lo & 7);
      bf16x8 a = *(const bf16x8*)(dbuf[cur] + row * 256 + slot * 16);
      mm = __builtin_amdgcn_mfma_f32_16x16x32_bf16(a, bq[kk], mm, 0, 0, 0);
    }
    // raw_j = exp(-50v^2 + 100*v*mu_j), mu_j = -0.95 + 0.1j.
    // middle-out chain from j=9 (mu=-0.05): intermediates <= e^45.1;
    // underflow only at tails where true value ~0. Two packed chains
    // cover the 4 elements -> v_pk_mul/v_pk_add.
#pragma unroll
    for (int p = 0; p < 2; ++p) {
      f32x2 v = {mm[p], mm[p + 2]};
      f32x2 m = v * L2E;
      f32x2 a10 = m * 10.0f;
      f32x2 G, Gi, t9;
      G.x = EXP2(a10.x);
      G.y = EXP2(a10.y);
      Gi.x = EXP2(-a10.x);
      Gi.y = EXP2(-a10.y);
      f32x2 e9 = m * (v * -50.0f - 5.0f);  // (-50v^2-5v)*log2e
      t9.x = EXP2(e9.x);
      t9.y = EXP2(e9.y);
      f32x2 tu = t9, td = t9;
      acc20[9] += t9;
#pragma unroll
      for (int j = 10; j < 20; ++j) { tu *= G; acc20[j] += tu; }
#pragma unroll
      for (int j = 8; j >= 0; --j) { td *= Gi; acc20[j] += td; }
    }
    asm volatile("s_waitcnt vmcnt(0)" ::: "memory");  // own prefetch drained
    __syncthreads();                                  // everyone's landed
  }

  // ---- exact-match kernel via integer equality (group 0 only; lane covers
  // docs 64*hi..64*hi+63; padding token 0 is a zero vector -> no match) ----
  int cnt = 0;
  if (g == 0) {
#pragma unroll 16
    for (int i = 0; i < 64; ++i) cnt += (dtok[hi * 64 + i] == myq) ? 1 : 0;
    cnt = (myq == 0) ? 0 : cnt;
    cnt += __shfl_xor(cnt, 16, 64);
    cnt += __shfl_xor(cnt, 32, 64);
  }

  // ---- horizontal fold + reduce over hi (lanes 16,32 apart share same q) ----
  float sa[20];
#pragma unroll
  for (int j = 0; j < 20; ++j) {
    float s2 = acc20[j].x + acc20[j].y;
    s2 += __shfl_xor(s2, 16, 64);
    s2 += __shfl_xor(s2, 32, 64);
    sa[j] = s2;
  }

  if (hi == 0) {
    int q = qs * 16 + lo;
#pragma unroll
    for (int j = 0; j < 20; ++j) kmbuf[g][q][j] = sa[j];
    kmbuf[g][q][20] = (g == 0) ? (float)cnt : 0.0f;
  }
  __syncthreads();

  // ---- km[j] = sum_q log(1 + C_j*rawsum) via native log2, C_j = exp(-50 mu^2)
  const float cA = -50.0f * L2E;
  if (tid < 84) {
    int j = tid % 21, c = tid / 21;
    float Cj = 1.0f;
    if (j < 20) {
      float mu = -0.95f + 0.1f * (float)j;
      Cj = EXP2(cA * mu * mu);
    }
    float s = 0.0f;
    for (int q = 0; q < 16; ++q) {
      float raw = kmbuf[0][c * 16 + q][j] + kmbuf[1][c * 16 + q][j];
      s += LOG2(fmaf(Cj, raw, 1.0f));
    }
    km2[c][j] = s * LN2;
  }
  __syncthreads();
  if (tid < 21)
    kmv[tid] = fmaxf(km2[0][tid] + km2[1][tid] + km2[2][tid] + km2[3][tid], 0.0f);
  __syncthreads();
  if (tid < 10) {
    float s = b1[tid];
    for (int j = 0; j < 21; ++j) s = fmaf(W1[tid * 21 + j], kmv[j], s);
    x1[tid] = fmaxf(s, 0.0f);
  }
  __syncthreads();
  if (tid < 5) {
    float s = b2[tid];
    for (int i = 0; i < 10; ++i) s = fmaf(W2[tid * 10 + i], x1[i], s);
    x2[tid] = s;
  }
  __syncthreads();
  if (tid == 0) {
    float s = b3[0];
    for (int i = 0; i < 5; ++i) s = fmaf(W3[i], x2[i], s);
    out[b] = s;
  }
}

extern "C" void kernel_launch(void* const* d_in, const int* in_sizes, int n_in,
                              void* d_out, int out_size, void* d_ws, size_t ws_size,
                              hipStream_t stream) {
  const int* query = (const int*)d_in[0];
  const int* doc = (const int*)d_in[1];
  const float* emb = (const float*)d_in[2];
  const float* W1 = (const float*)d_in[3];
  const float* b1 = (const float*)d_in[4];
  const float* W2 = (const float*)d_in[5];
  const float* b2 = (const float*)d_in[6];
  const float* W3 = (const float*)d_in[7];
  const float* b3 = (const float*)d_in[8];
  float* out = (float*)d_out;
  unsigned* embN = (unsigned*)d_ws;  // 50000*64 uints = 12.8 MB bf16 table

  hipLaunchKernelGGL(knrm_norm, dim3(1024), dim3(256), 0, stream, emb, embN);
  hipLaunchKernelGGL(knrm_main, dim3(1024), dim3(512), 0, stream, query, doc, embN,
                     W1, b1, W2, b2, W3, b3, out);
}

// Round 8
// 41.118 us; speedup vs baseline: 1.8282x; 1.8282x over previous
//
#include <hip/hip_runtime.h>
#include <hip/hip_bf16.h>

#define L2E 1.4426950408889634f
#define LN2 0.6931471805599453f

#if defined(__has_builtin)
#if __has_builtin(__builtin_amdgcn_exp2f)
#define EXP2(x) __builtin_amdgcn_exp2f(x)
#else
#define EXP2(x) exp2f(x)
#endif
#if __has_builtin(__builtin_amdgcn_logf)
#define LOG2(x) __builtin_amdgcn_logf(x)
#else
#define LOG2(x) __log2f(x)
#endif
#else
#define EXP2(x) exp2f(x)
#define LOG2(x) __log2f(x)
#endif

typedef __attribute__((ext_vector_type(8))) short bf16x8;
typedef __attribute__((ext_vector_type(4))) float f32x4;
typedef __attribute__((ext_vector_type(2))) float f32x2;

__device__ __forceinline__ void gld_lds16(const void* g, void* l) {
  __builtin_amdgcn_global_load_lds(
      (const __attribute__((address_space(1))) void*)g,
      (__attribute__((address_space(3))) void*)l, 16, 0, 0);
}

__device__ __forceinline__ unsigned bf16rne(float f) {
  unsigned u = __float_as_uint(f);
  return (u + 0x7fffu + ((u >> 16) & 1u)) >> 16;
}

// Kernel A: L2-normalize embedding table -> packed bf16 (2 per uint32).
// float4 loads, 2 rows per wave. At HBM floor (~6.1us for 38.4MB).
__global__ __launch_bounds__(256) void knrm_norm(const float* __restrict__ emb,
                                                 unsigned* __restrict__ embN) {
  const int t = threadIdx.x;
  const int l = t & 31;
  const int sub = (t >> 5) & 1;
  int wv = blockIdx.x * 4 + (t >> 6);
  const int nW = gridDim.x * 4;
  for (int rp = wv; rp < 25000; rp += nW) {
    int r = rp * 2 + sub;
    float4 v = *(const float4*)(emb + (size_t)r * 128 + l * 4);
    float ss = v.x * v.x + v.y * v.y + v.z * v.z + v.w * v.w;
#pragma unroll
    for (int m = 1; m < 32; m <<= 1) ss += __shfl_xor(ss, m, 64);  // within 32-lane half
    float sc = 1.0f / fmaxf(sqrtf(ss), 1e-12f);
    uint2 o;
    o.x = bf16rne(v.x * sc) | (bf16rne(v.y * sc) << 16);
    o.y = bf16rne(v.z * sc) | (bf16rne(v.w * sc) << 16);
    *(uint2*)(embN + (size_t)r * 64 + l * 2) = o;
  }
}

// Kernel B: per batch item, 256 threads (4 waves). Docs staged in 16-row
// SIXTEENTHS (double-buffered LDS, exactly one global_load_lds per thread
// per stage) -> LDS ~15KB -> 8 blocks/CU -> 32 waves/CU at VGPR<=64.
// Wave w computes q-strip w (16 q rows) vs the staged 16 doc rows via one
// mfma_f32_16x16x32_bf16 tile per stage. 20 Gaussian kernels via middle-out
// geometric chain, packed f32x2. Exact-match kernel = integer token compare.
__global__ __launch_bounds__(256, 4) void knrm_main(
    const int* __restrict__ query, const int* __restrict__ doc,
    const unsigned* __restrict__ embN,
    const float* __restrict__ W1, const float* __restrict__ b1,
    const float* __restrict__ W2, const float* __restrict__ b2,
    const float* __restrict__ W3, const float* __restrict__ b3,
    float* __restrict__ out) {
  __shared__ __align__(16) char dbuf[2][16 * 256];  // 2 x 4KB doc sixteenths
  __shared__ float kmbuf[64 * 21];
  __shared__ int dtok[256];
  __shared__ float km2[4][21];
  __shared__ float kmv[21];
  __shared__ float x1[10];
  __shared__ float x2[5];

  const int b = blockIdx.x;
  const int tid = threadIdx.x;
  const int w = tid >> 6;  // wave = q-strip
  const int lane = tid & 63;
  const int lo = lane & 15, hi = lane >> 4;
  const char* embB = (const char*)embN;  // 256 B per vocab row (128 bf16)

  dtok[tid] = doc[b * 256 + tid];

  // ---- Q fragments straight from global (B-operand: col=lo=q, k=8*hi+e) ----
  const int myq = query[b * 64 + w * 16 + lo];
  bf16x8 bq[4];
#pragma unroll
  for (int kk = 0; kk < 4; ++kk)
    bq[kk] = *(const bf16x8*)(embB + (size_t)myq * 256 + kk * 64 + hi * 16);

  // ---- staging geometry: thread t owns 16B slot (t&15) of stage-row (t>>4).
  // LDS rows are 256B; slots XOR-swizzled: LDS[row][s] = G[row][s^(row&7)].
  // global_load_lds writes linearly (wave-uniform base + lane*16): wave w
  // covers rows w*4..w*4+3, and t>>4 == w*4 + (lane>>4). Source pre-swizzled.
  const int srow = tid >> 4;                   // 0..15
  const int sslot = (tid & 15) ^ (srow & 7);   // pre-swizzled source slot
  {
    int tok = doc[b * 256 + srow];  // dtok not yet visible (no barrier yet)
    gld_lds16(embB + (size_t)tok * 256 + sslot * 16, dbuf[0] + w * 1024);
  }
  asm volatile("s_waitcnt vmcnt(0)" ::: "memory");
  __syncthreads();

  f32x2 acc20[20];  // packed accumulators: .x sums elems (e=0,2), .y (e=1,3)
#pragma unroll
  for (int j = 0; j < 20; ++j) acc20[j] = (f32x2){0.0f, 0.0f};

#pragma unroll 1
  for (int s = 0; s < 16; ++s) {
    const int cur = s & 1;
    // prefetch next sixteenth into the other buffer (overlaps compute below;
    // safe: barrier ending stage s-1 guaranteed all reads of it finished)
    if (s < 15) {
      int tok = dtok[(s + 1) * 16 + srow];
      gld_lds16(embB + (size_t)tok * 256 + sslot * 16, dbuf[cur ^ 1] + w * 1024);
    }
    // one 16x16 tile: doc rows s*16..s*16+15 vs q-strip w
    f32x4 mm = {0.0f, 0.0f, 0.0f, 0.0f};
#pragma unroll
    for (int kk = 0; kk < 4; ++kk) {
      int slot = (kk * 4 + hi) ^ (lo & 7);  // A-operand: row=lo, k=8*hi+e
      bf16x8 a = *(const bf16x8*)(dbuf[cur] + lo * 256 + slot * 16);
      mm = __builtin_amdgcn_mfma_f32_16x16x32_bf16(a, bq[kk], mm, 0, 0, 0);
    }
    // mm[e]: doc = s*16 + 4*hi + e, q = w*16 + lo
    // raw_j = exp(-50v^2 + 100*v*mu_j), mu_j = -0.95 + 0.1j.
    // middle-out chain from j=9 (mu=-0.05): intermediates <= e^45.1;
    // underflow only at tails where true value ~0 (both directions decay).
    // Two packed chains cover the 4 elements -> v_pk_mul/v_pk_add.
#pragma unroll
    for (int p = 0; p < 2; ++p) {
      f32x2 v = {mm[p], mm[p + 2]};
      f32x2 m = v * L2E;
      f32x2 a10 = m * 10.0f;
      f32x2 G, Gi, t9;
      G.x = EXP2(a10.x);
      G.y = EXP2(a10.y);
      Gi.x = EXP2(-a10.x);
      Gi.y = EXP2(-a10.y);
      f32x2 e9 = m * (v * -50.0f - 5.0f);  // (-50v^2-5v)*log2e
      t9.x = EXP2(e9.x);
      t9.y = EXP2(e9.y);
      f32x2 tu = t9, td = t9;
      acc20[9] += t9;
#pragma unroll
      for (int j = 10; j < 20; ++j) { tu *= G; acc20[j] += tu; }
#pragma unroll
      for (int j = 8; j >= 0; --j) { td *= Gi; acc20[j] += td; }
    }
    asm volatile("s_waitcnt vmcnt(0)" ::: "memory");  // own prefetch drained
    __syncthreads();                                  // everyone's landed
  }

  // ---- exact-match kernel via integer equality (lane covers docs 64*hi..+63;
  // padding token 0 is a zero vector -> cosine 0, never matches) ----
  int cnt = 0;
#pragma unroll 16
  for (int i = 0; i < 64; ++i) cnt += (dtok[hi * 64 + i] == myq) ? 1 : 0;
  cnt = (myq == 0) ? 0 : cnt;
  cnt += __shfl_xor(cnt, 16, 64);
  cnt += __shfl_xor(cnt, 32, 64);

  // ---- horizontal fold + reduce over hi (lanes 16,32 apart share same q) ----
  float sa[20];
#pragma unroll
  for (int j = 0; j < 20; ++j) {
    float s2 = acc20[j].x + acc20[j].y;
    s2 += __shfl_xor(s2, 16, 64);
    s2 += __shfl_xor(s2, 32, 64);
    sa[j] = s2;
  }

  if (hi == 0) {
    int q = w * 16 + lo;
#pragma unroll
    for (int j = 0; j < 20; ++j) kmbuf[q * 21 + j] = sa[j];
    kmbuf[q * 21 + 20] = (float)cnt;
  }
  __syncthreads();

  // ---- km[j] = sum_q log(1 + C_j*rawsum) via native log2, C_j = exp(-50 mu^2)
  const float cA = -50.0f * L2E;
  if (tid < 84) {
    int j = tid % 21, c = tid / 21;
    float Cj = 1.0f;
    if (j < 20) {
      float mu = -0.95f + 0.1f * (float)j;
      Cj = EXP2(cA * mu * mu);
    }
    float s = 0.0f;
    for (int q = 0; q < 16; ++q)
      s += LOG2(fmaf(Cj, kmbuf[(c * 16 + q) * 21 + j], 1.0f));
    km2[c][j] = s * LN2;
  }
  __syncthreads();
  if (tid < 21)
    kmv[tid] = fmaxf(km2[0][tid] + km2[1][tid] + km2[2][tid] + km2[3][tid], 0.0f);
  __syncthreads();
  if (tid < 10) {
    float s = b1[tid];
    for (int j = 0; j < 21; ++j) s = fmaf(W1[tid * 21 + j], kmv[j], s);
    x1[tid] = fmaxf(s, 0.0f);
  }
  __syncthreads();
  if (tid < 5) {
    float s = b2[tid];
    for (int i = 0; i < 10; ++i) s = fmaf(W2[tid * 10 + i], x1[i], s);
    x2[tid] = s;
  }
  __syncthreads();
  if (tid == 0) {
    float s = b3[0];
    for (int i = 0; i < 5; ++i) s = fmaf(W3[i], x2[i], s);
    out[b] = s;
  }
}

extern "C" void kernel_launch(void* const* d_in, const int* in_sizes, int n_in,
                              void* d_out, int out_size, void* d_ws, size_t ws_size,
                              hipStream_t stream) {
  const int* query = (const int*)d_in[0];
  const int* doc = (const int*)d_in[1];
  const float* emb = (const float*)d_in[2];
  const float* W1 = (const float*)d_in[3];
  const float* b1 = (const float*)d_in[4];
  const float* W2 = (const float*)d_in[5];
  const float* b2 = (const float*)d_in[6];
  const float* W3 = (const float*)d_in[7];
  const float* b3 = (const float*)d_in[8];
  float* out = (float*)d_out;
  unsigned* embN = (unsigned*)d_ws;  // 50000*64 uints = 12.8 MB bf16 table

  hipLaunchKernelGGL(knrm_norm, dim3(1024), dim3(256), 0, stream, emb, embN);
  hipLaunchKernelGGL(knrm_main, dim3(1024), dim3(256), 0, stream, query, doc, embN,
                     W1, b1, W2, b2, W3, b3, out);
}